// Round 4
// baseline (539.260 us; speedup 1.0000x reference)
//
#include <hip/hip_runtime.h>
#include <hip/hip_cooperative_groups.h>

namespace cg = cooperative_groups;

// Retention forward, chunkwise-linear, single cooperative kernel.
// O[i] = intra-chunk + scale*lam^(i_local) * q_i . S_c
// S_c = lam^C S_{c-1} + U_{c-1},  U_c[d][e] = sum_j lam^(C-j) K[j][d] V[j][e]
// Phase A: per-chunk U_c + intra-O (regs). grid.sync.
// Phase B: elementwise scan over chunks -> S as bf16 hi/lo. grid.sync.
// Phase C: O += scale*lam^i * Q.(S_hi + S_lo); store.

#define S_LEN 2048
#define DHEAD 64
#define CHUNK 64
#define NC    32
#define BH    32
#define LDK   72

typedef float  f32x4  __attribute__((ext_vector_type(4)));
typedef short  bf16x8 __attribute__((ext_vector_type(8)));
typedef unsigned short u16x8 __attribute__((ext_vector_type(8)));

static __device__ __forceinline__ unsigned short f2bf(float f) {
    unsigned int u = __float_as_uint(f);
    u += 0x7FFFu + ((u >> 16) & 1u);
    return (unsigned short)(u >> 16);
}
static __device__ __forceinline__ float bf2f(unsigned short h) {
    return __uint_as_float((unsigned int)h << 16);
}

__global__ __launch_bounds__(256, 4)
void ret_fused(const float* __restrict__ qg, const float* __restrict__ kg,
               const float* __restrict__ vg, float* __restrict__ Ug,
               unsigned short* __restrict__ Shg, unsigned short* __restrict__ Slg,
               float* __restrict__ og) {
    const int c  = (int)blockIdx.x, bh = (int)blockIdx.y, h = bh & 15;
    const int tid = (int)threadIdx.x;
    const int wv = tid >> 6, ln = tid & 63, quad = ln >> 4, lnlo = ln & 15;
    const float sh    = log2f(1.0f - exp2f(-5.0f - (float)h));   // < 0
    const float scale = 0.125f;

    // 3 LDS buffers, 27.6 KB total (4 blocks/CU co-residency for coop launch)
    __shared__ __align__(16) unsigned short Ks[CHUNK * LDK];    // A: K [pos][d];   C: S_lo^T [e][d]
    __shared__ __align__(16) unsigned short Vt[CHUNK * LDK];    // V^T [e][pos]
    __shared__ __align__(16) unsigned short KtWs[CHUNK * LDK];  // A: lam-weighted K^T [d][j] -> Ws; C: S_hi^T [e][d]

    const size_t cb = (size_t)bh * S_LEN * DHEAD + (size_t)c * CHUNK * DHEAD;
    const float* qp = qg + cb;
    const float* kp = kg + cb;
    const float* vp = vg + cb;
    float*       op = og + cb;

    // ================= Phase A =================
    // stage K [pos][d] (coalesced float4)
    {
        const int kr = tid >> 2, kc0 = (tid & 3) * 16;
        const float* p = kp + (size_t)kr * DHEAD + kc0;
        const f32x4 x0 = *(const f32x4*)(p + 0);
        const f32x4 x1 = *(const f32x4*)(p + 4);
        const f32x4 x2 = *(const f32x4*)(p + 8);
        const f32x4 x3 = *(const f32x4*)(p + 12);
        u16x8 w0, w1;
        w0[0]=f2bf(x0[0]); w0[1]=f2bf(x0[1]); w0[2]=f2bf(x0[2]); w0[3]=f2bf(x0[3]);
        w0[4]=f2bf(x1[0]); w0[5]=f2bf(x1[1]); w0[6]=f2bf(x1[2]); w0[7]=f2bf(x1[3]);
        w1[0]=f2bf(x2[0]); w1[1]=f2bf(x2[1]); w1[2]=f2bf(x2[2]); w1[3]=f2bf(x2[3]);
        w1[4]=f2bf(x3[0]); w1[5]=f2bf(x3[1]); w1[6]=f2bf(x3[2]); w1[7]=f2bf(x3[3]);
        *(u16x8*)&Ks[kr * LDK + kc0]     = w0;
        *(u16x8*)&Ks[kr * LDK + kc0 + 8] = w1;
    }
    // stage V^T [e][pos] and lam-weighted K^T [d][j] (coalesced-per-j scalar)
#pragma unroll
    for (int i = 0; i < 2; ++i) {
        const int pos0 = wv * 8 + i * 32;
        const float* pV = vp + (size_t)pos0 * DHEAD + ln;
        const float* pK = kp + (size_t)pos0 * DHEAD + ln;   // L1-hot (just read above)
        u16x8 tv, tk;
#pragma unroll
        for (int j = 0; j < 8; ++j) {
            tv[j] = f2bf(pV[(size_t)j * DHEAD]);
            const float w = exp2f(sh * (float)(CHUNK - pos0 - j));
            tk[j] = f2bf(pK[(size_t)j * DHEAD] * w);
        }
        *(u16x8*)&Vt[ln * LDK + pos0]   = tv;
        *(u16x8*)&KtWs[ln * LDK + pos0] = tk;
    }
    // Q A-fragments (held across all phases)
    bf16x8 aQ[2];
    {
        const float* qrow = qp + (size_t)(wv * 16 + lnlo) * DHEAD;
#pragma unroll
        for (int ks = 0; ks < 2; ++ks) {
            const float* p = qrow + ks * 32 + quad * 8;
            bf16x8 a;
#pragma unroll
            for (int j = 0; j < 8; ++j) a[j] = (short)f2bf(p[j]);
            aQ[ks] = a;
        }
    }
    float rf[4];
#pragma unroll
    for (int r = 0; r < 4; ++r) rf[r] = exp2f((float)(wv * 16 + quad * 4 + r) * sh);

    __syncthreads();

    // U_c = (lam-weighted K)^T V : A[m=d][k=j] from KtWs rows, B[k=j][n=e] from Vt rows
    {
        bf16x8 aK[2];
#pragma unroll
        for (int ks = 0; ks < 2; ++ks)
            aK[ks] = *(const bf16x8*)&KtWs[(wv * 16 + lnlo) * LDK + ks * 32 + quad * 8];
        float* up = Ug + ((size_t)(bh * NC + c) << 12);
#pragma unroll
        for (int nt = 0; nt < 4; ++nt) {
            f32x4 acc = (f32x4){0.f, 0.f, 0.f, 0.f};
#pragma unroll
            for (int ks = 0; ks < 2; ++ks) {
                const bf16x8 bv = *(const bf16x8*)&Vt[(nt * 16 + lnlo) * LDK + ks * 32 + quad * 8];
                acc = __builtin_amdgcn_mfma_f32_16x16x32_bf16(aK[ks], bv, acc, 0, 0, 0);
            }
            // U^T[e][d], contiguous d (float4 over r)
            *(f32x4*)&up[(nt * 16 + lnlo) * 64 + wv * 16 + quad * 4] = acc;
        }
    }

    // intra scores S = Q K^T
    f32x4 acc[4];
#pragma unroll
    for (int nt = 0; nt < 4; ++nt) {
        f32x4 a = (f32x4){0.f, 0.f, 0.f, 0.f};
#pragma unroll
        for (int ks = 0; ks < 2; ++ks) {
            const bf16x8 bk = *(const bf16x8*)&Ks[(nt * 16 + lnlo) * LDK + ks * 32 + quad * 8];
            a = __builtin_amdgcn_mfma_f32_16x16x32_bf16(aQ[ks], bk, a, 0, 0, 0);
        }
        acc[nt] = a;
    }

    // decay*scale*causal -> Ws (own wave's 16-row slice of KtWs; wave read only its
    // own slice as A-frags above, so no cross-wave hazard, no barrier needed)
#pragma unroll
    for (int nt = 0; nt < 4; ++nt) {
        const int jn = nt * 16 + lnlo;
        const float cf = scale * exp2f(-(float)jn * sh);
#pragma unroll
        for (int r = 0; r < 4; ++r) {
            const int ri = wv * 16 + quad * 4 + r;
            float wgt = acc[nt][r] * rf[r] * cf;
            if (ri < jn) wgt = 0.0f;
            KtWs[ri * LDK + jn] = f2bf(wgt);
        }
    }
    const bf16x8 aW0 = *(const bf16x8*)&KtWs[(wv * 16 + lnlo) * LDK + quad * 8];
    const bf16x8 aW1 = *(const bf16x8*)&KtWs[(wv * 16 + lnlo) * LDK + 32 + quad * 8];

    // intra O = P V (kept in registers across the grid syncs)
    f32x4 o[4];
#pragma unroll
    for (int nt = 0; nt < 4; ++nt) {
        f32x4 a = (f32x4){0.f, 0.f, 0.f, 0.f};
        const bf16x8 bv0 = *(const bf16x8*)&Vt[(nt * 16 + lnlo) * LDK + quad * 8];
        const bf16x8 bv1 = *(const bf16x8*)&Vt[(nt * 16 + lnlo) * LDK + 32 + quad * 8];
        a = __builtin_amdgcn_mfma_f32_16x16x32_bf16(aW0, bv0, a, 0, 0, 0);
        a = __builtin_amdgcn_mfma_f32_16x16x32_bf16(aW1, bv1, a, 0, 0, 0);
        o[nt] = a;
    }

    __threadfence();
    cg::this_grid().sync();

    // ================= Phase B: scan =================
    // block (c,bh) scans elems [c*128, c*128+128) of head bh; threads 0..127
    if (tid < 128) {
        const int elem = c * 128 + tid;
        const float*    up  = Ug  + ((size_t)(bh * NC) << 12) + elem;
        unsigned short* shp = Shg + ((size_t)(bh * NC) << 12) + elem;
        unsigned short* slp = Slg + ((size_t)(bh * NC) << 12) + elem;
        const float lamC = exp2f(sh * (float)CHUNK);
        float S = 0.0f;
        float u = up[0];
        for (int cc = 0; cc < NC; ++cc) {
            const float un = (cc + 1 < NC) ? up[(size_t)(cc + 1) << 12] : 0.0f;
            const unsigned short hi = f2bf(S);
            shp[(size_t)cc << 12] = hi;
            slp[(size_t)cc << 12] = f2bf(S - bf2f(hi));
            S = lamC * S + u;
            u = un;
        }
    }

    __threadfence();
    cg::this_grid().sync();

    // ================= Phase C: cross =================
    // stage S_hi^T -> KtWs, S_lo^T -> Ks (both dead after phase A)
    {
        const size_t sb = ((size_t)(bh * NC + c) << 12) + (size_t)tid * 16;
        const int r = tid >> 2, ccol = (tid & 3) * 16;
        *(u16x8*)&KtWs[r * LDK + ccol]     = *(const u16x8*)(Shg + sb);
        *(u16x8*)&KtWs[r * LDK + ccol + 8] = *(const u16x8*)(Shg + sb + 8);
        *(u16x8*)&Ks[r * LDK + ccol]       = *(const u16x8*)(Slg + sb);
        *(u16x8*)&Ks[r * LDK + ccol + 8]   = *(const u16x8*)(Slg + sb + 8);
    }
    __syncthreads();

#pragma unroll
    for (int nt = 0; nt < 4; ++nt) {
        f32x4 a = (f32x4){0.f, 0.f, 0.f, 0.f};
#pragma unroll
        for (int ks = 0; ks < 2; ++ks) {
            const bf16x8 bh_ = *(const bf16x8*)&KtWs[(nt * 16 + lnlo) * LDK + ks * 32 + quad * 8];
            a = __builtin_amdgcn_mfma_f32_16x16x32_bf16(aQ[ks], bh_, a, 0, 0, 0);
        }
#pragma unroll
        for (int ks = 0; ks < 2; ++ks) {
            const bf16x8 bl_ = *(const bf16x8*)&Ks[(nt * 16 + lnlo) * LDK + ks * 32 + quad * 8];
            a = __builtin_amdgcn_mfma_f32_16x16x32_bf16(aQ[ks], bl_, a, 0, 0, 0);
        }
#pragma unroll
        for (int r = 0; r < 4; ++r) o[nt][r] += a[r] * rf[r] * scale;
    }

    // epilogue
#pragma unroll
    for (int nt = 0; nt < 4; ++nt)
#pragma unroll
        for (int r = 0; r < 4; ++r)
            op[(size_t)(wv * 16 + quad * 4 + r) * DHEAD + nt * 16 + lnlo] = o[nt][r];
}

// ================= Fallback: round-3 three-kernel path =================
__global__ __launch_bounds__(256)
void ret_p1(const float* __restrict__ kg, const float* __restrict__ vg,
            float* __restrict__ Ug) {
    const int c  = (int)blockIdx.x, bh = (int)blockIdx.y, h = bh & 15;
    const int tid = (int)threadIdx.x;
    const int wv = tid >> 6, ln = tid & 63, quad = ln >> 4, lnlo = ln & 15;
    const float sh = log2f(1.0f - exp2f(-5.0f - (float)h));
    __shared__ __align__(16) unsigned short Kt[CHUNK * LDK];
    __shared__ __align__(16) unsigned short Vt[CHUNK * LDK];
    const size_t cb = (size_t)bh * S_LEN * DHEAD + (size_t)c * CHUNK * DHEAD;
    const float* kp = kg + cb;
    const float* vp = vg + cb;
#pragma unroll
    for (int i = 0; i < 2; ++i) {
        const int pos0 = wv * 8 + i * 32;
        const float* pK = kp + (size_t)pos0 * DHEAD + ln;
        const float* pV = vp + (size_t)pos0 * DHEAD + ln;
        u16x8 tk, tv;
#pragma unroll
        for (int j = 0; j < 8; ++j) {
            const float w = exp2f(sh * (float)(CHUNK - pos0 - j));
            tk[j] = f2bf(pK[(size_t)j * DHEAD] * w);
            tv[j] = f2bf(pV[(size_t)j * DHEAD]);
        }
        *(u16x8*)&Kt[ln * LDK + pos0] = tk;
        *(u16x8*)&Vt[ln * LDK + pos0] = tv;
    }
    __syncthreads();
    bf16x8 aK[2];
#pragma unroll
    for (int ks = 0; ks < 2; ++ks)
        aK[ks] = *(const bf16x8*)&Kt[(wv * 16 + lnlo) * LDK + ks * 32 + quad * 8];
    float* up = Ug + ((size_t)(bh * NC + c) << 12);
#pragma unroll
    for (int nt = 0; nt < 4; ++nt) {
        f32x4 acc = (f32x4){0.f, 0.f, 0.f, 0.f};
#pragma unroll
        for (int ks = 0; ks < 2; ++ks) {
            const bf16x8 bv = *(const bf16x8*)&Vt[(nt * 16 + lnlo) * LDK + ks * 32 + quad * 8];
            acc = __builtin_amdgcn_mfma_f32_16x16x32_bf16(aK[ks], bv, acc, 0, 0, 0);
        }
        *(f32x4*)&up[(nt * 16 + lnlo) * 64 + wv * 16 + quad * 4] = acc;
    }
}

__global__ __launch_bounds__(256)
void ret_p2(const float* __restrict__ Ug,
            unsigned short* __restrict__ Shg, unsigned short* __restrict__ Slg) {
    const int eb = (int)blockIdx.x, bh = (int)blockIdx.y, h = bh & 15;
    const float sh   = log2f(1.0f - exp2f(-5.0f - (float)h));
    const float lamC = exp2f(sh * (float)CHUNK);
    const int elem = eb * 256 + (int)threadIdx.x;
    const float* up     = Ug  + ((size_t)(bh * NC) << 12) + elem;
    unsigned short* shp = Shg + ((size_t)(bh * NC) << 12) + elem;
    unsigned short* slp = Slg + ((size_t)(bh * NC) << 12) + elem;
    float S = 0.0f;
    float u = up[0];
    for (int c = 0; c < NC; ++c) {
        const float un = (c + 1 < NC) ? up[(size_t)(c + 1) << 12] : 0.0f;
        const unsigned short hi = f2bf(S);
        shp[(size_t)c << 12] = hi;
        slp[(size_t)c << 12] = f2bf(S - bf2f(hi));
        S = lamC * S + u;
        u = un;
    }
}

__global__ __launch_bounds__(256)
void ret_p3(const float* __restrict__ qg, const float* __restrict__ kg,
            const float* __restrict__ vg,
            const unsigned short* __restrict__ Shg,
            const unsigned short* __restrict__ Slg,
            float* __restrict__ og) {
    const int c  = (int)blockIdx.x, bh = (int)blockIdx.y, h = bh & 15;
    const int tid = (int)threadIdx.x;
    const int wv = tid >> 6, ln = tid & 63, quad = ln >> 4, lnlo = ln & 15;
    const float sh    = log2f(1.0f - exp2f(-5.0f - (float)h));
    const float scale = 0.125f;
    __shared__ __align__(16) unsigned short Ks[CHUNK * LDK];
    __shared__ __align__(16) unsigned short Vt[CHUNK * LDK];
    __shared__ __align__(16) unsigned short ShL[CHUNK * LDK];
    __shared__ __align__(16) unsigned short SlL[CHUNK * LDK];
    const size_t cb = (size_t)bh * S_LEN * DHEAD + (size_t)c * CHUNK * DHEAD;
    const float* qp = qg + cb;
    const float* kp = kg + cb;
    const float* vp = vg + cb;
    float*       op = og + cb;
    {
        const int kr = tid >> 2, kc0 = (tid & 3) * 16;
        const float* p = kp + (size_t)kr * DHEAD + kc0;
        const f32x4 x0 = *(const f32x4*)(p + 0);
        const f32x4 x1 = *(const f32x4*)(p + 4);
        const f32x4 x2 = *(const f32x4*)(p + 8);
        const f32x4 x3 = *(const f32x4*)(p + 12);
        u16x8 w0, w1;
        w0[0]=f2bf(x0[0]); w0[1]=f2bf(x0[1]); w0[2]=f2bf(x0[2]); w0[3]=f2bf(x0[3]);
        w0[4]=f2bf(x1[0]); w0[5]=f2bf(x1[1]); w0[6]=f2bf(x1[2]); w0[7]=f2bf(x1[3]);
        w1[0]=f2bf(x2[0]); w1[1]=f2bf(x2[1]); w1[2]=f2bf(x2[2]); w1[3]=f2bf(x2[3]);
        w1[4]=f2bf(x3[0]); w1[5]=f2bf(x3[1]); w1[6]=f2bf(x3[2]); w1[7]=f2bf(x3[3]);
        *(u16x8*)&Ks[kr * LDK + kc0]     = w0;
        *(u16x8*)&Ks[kr * LDK + kc0 + 8] = w1;
    }
#pragma unroll
    for (int i = 0; i < 2; ++i) {
        const int pos0 = wv * 8 + i * 32;
        const float* p = vp + (size_t)pos0 * DHEAD + ln;
        u16x8 t;
#pragma unroll
        for (int j = 0; j < 8; ++j) t[j] = f2bf(p[(size_t)j * DHEAD]);
        *(u16x8*)&Vt[ln * LDK + pos0] = t;
    }
    {
        const size_t sb = ((size_t)(bh * NC + c) << 12) + (size_t)tid * 16;
        const int r = tid >> 2, cc = (tid & 3) * 16;
        *(u16x8*)&ShL[r * LDK + cc]     = *(const u16x8*)(Shg + sb);
        *(u16x8*)&ShL[r * LDK + cc + 8] = *(const u16x8*)(Shg + sb + 8);
        *(u16x8*)&SlL[r * LDK + cc]     = *(const u16x8*)(Slg + sb);
        *(u16x8*)&SlL[r * LDK + cc + 8] = *(const u16x8*)(Slg + sb + 8);
    }
    bf16x8 aQ[2];
    {
        const float* qrow = qp + (size_t)(wv * 16 + lnlo) * DHEAD;
#pragma unroll
        for (int ks = 0; ks < 2; ++ks) {
            const float* p = qrow + ks * 32 + quad * 8;
            bf16x8 a;
#pragma unroll
            for (int j = 0; j < 8; ++j) a[j] = (short)f2bf(p[j]);
            aQ[ks] = a;
        }
    }
    float rf[4];
#pragma unroll
    for (int r = 0; r < 4; ++r) rf[r] = exp2f((float)(wv * 16 + quad * 4 + r) * sh);
    __syncthreads();
    f32x4 o[4];
#pragma unroll
    for (int nt = 0; nt < 4; ++nt) {
        f32x4 a = (f32x4){0.f, 0.f, 0.f, 0.f};
#pragma unroll
        for (int ks = 0; ks < 2; ++ks) {
            const bf16x8 bh_ = *(const bf16x8*)&ShL[(nt * 16 + lnlo) * LDK + ks * 32 + quad * 8];
            a = __builtin_amdgcn_mfma_f32_16x16x32_bf16(aQ[ks], bh_, a, 0, 0, 0);
        }
#pragma unroll
        for (int ks = 0; ks < 2; ++ks) {
            const bf16x8 bl_ = *(const bf16x8*)&SlL[(nt * 16 + lnlo) * LDK + ks * 32 + quad * 8];
            a = __builtin_amdgcn_mfma_f32_16x16x32_bf16(aQ[ks], bl_, a, 0, 0, 0);
        }
        o[nt] = a;
    }
    f32x4 acc[4];
#pragma unroll
    for (int nt = 0; nt < 4; ++nt) {
        f32x4 a = (f32x4){0.f, 0.f, 0.f, 0.f};
#pragma unroll
        for (int ks = 0; ks < 2; ++ks) {
            const bf16x8 bk = *(const bf16x8*)&Ks[(nt * 16 + lnlo) * LDK + ks * 32 + quad * 8];
            a = __builtin_amdgcn_mfma_f32_16x16x32_bf16(aQ[ks], bk, a, 0, 0, 0);
        }
        acc[nt] = a;
    }
#pragma unroll
    for (int nt = 0; nt < 4; ++nt)
#pragma unroll
        for (int r = 0; r < 4; ++r) o[nt][r] *= rf[r] * scale;
    __syncthreads();
#pragma unroll
    for (int nt = 0; nt < 4; ++nt) {
        const int jn = nt * 16 + lnlo;
        const float cf = scale * exp2f(-(float)jn * sh);
#pragma unroll
        for (int r = 0; r < 4; ++r) {
            const int ri = wv * 16 + quad * 4 + r;
            float wgt = acc[nt][r] * rf[r] * cf;
            if (ri < jn) wgt = 0.0f;
            ShL[ri * LDK + jn] = f2bf(wgt);
        }
    }
    const bf16x8 aW0 = *(const bf16x8*)&ShL[(wv * 16 + lnlo) * LDK + quad * 8];
    const bf16x8 aW1 = *(const bf16x8*)&ShL[(wv * 16 + lnlo) * LDK + 32 + quad * 8];
#pragma unroll
    for (int nt = 0; nt < 4; ++nt) {
        const bf16x8 bv0 = *(const bf16x8*)&Vt[(nt * 16 + lnlo) * LDK + quad * 8];
        const bf16x8 bv1 = *(const bf16x8*)&Vt[(nt * 16 + lnlo) * LDK + 32 + quad * 8];
        o[nt] = __builtin_amdgcn_mfma_f32_16x16x32_bf16(aW0, bv0, o[nt], 0, 0, 0);
        o[nt] = __builtin_amdgcn_mfma_f32_16x16x32_bf16(aW1, bv1, o[nt], 0, 0, 0);
    }
#pragma unroll
    for (int nt = 0; nt < 4; ++nt)
#pragma unroll
        for (int r = 0; r < 4; ++r)
            op[(size_t)(wv * 16 + quad * 4 + r) * DHEAD + nt * 16 + lnlo] = o[nt][r];
}

extern "C" void kernel_launch(void* const* d_in, const int* in_sizes, int n_in,
                              void* d_out, int out_size, void* d_ws, size_t ws_size,
                              hipStream_t stream) {
    (void)in_sizes; (void)n_in; (void)out_size; (void)ws_size;
    const float* q = (const float*)d_in[0];
    const float* k = (const float*)d_in[1];
    const float* v = (const float*)d_in[2];
    float* o = (float*)d_out;

    const size_t U_BYTES = (size_t)BH * NC * 4096 * 4;   // 16 MB
    const size_t S_BYTES = (size_t)BH * NC * 4096 * 2;   //  8 MB each
    float*          Ug  = (float*)d_ws;
    unsigned short* Shg = (unsigned short*)((char*)d_ws + U_BYTES);
    unsigned short* Slg = (unsigned short*)((char*)d_ws + U_BYTES + S_BYTES);

    void* args[] = {(void*)&q, (void*)&k, (void*)&v,
                    (void*)&Ug, (void*)&Shg, (void*)&Slg, (void*)&o};
    hipError_t err = hipLaunchCooperativeKernel((const void*)ret_fused,
                                                dim3(NC, BH, 1), dim3(256, 1, 1),
                                                args, 0, stream);
    if (err != hipSuccess) {
        // fallback: 3-kernel path (round-3 behavior)
        dim3 blk(256, 1, 1);
        ret_p1<<<dim3(NC, BH, 1), blk, 0, stream>>>(k, v, Ug);
        ret_p2<<<dim3(16, BH, 1), blk, 0, stream>>>(Ug, Shg, Slg);
        ret_p3<<<dim3(NC, BH, 1), blk, 0, stream>>>(q, k, v, Shg, Slg, o);
    }
}

// Round 5
// 142.040 us; speedup vs baseline: 3.7965x; 3.7965x over previous
//
#include <hip/hip_runtime.h>

// Retention forward, chunkwise-linear, 2 kernels (NO cooperative sync — grid.sync
// measured at ~430us on this chip, round 4).
// p1: U_c[d][e] = sum_j lam^(C-j) K[j][d] V[j][e]  (per-chunk MFMA)  -> ws (fp32)
// p3: per (bh,c): S_c = sum_{cc<c} lamC^(c-1-cc) U_cc  (in-block scan, L2-fed);
//     O = intra-chunk + scale*lam^(i_local) * Q.(S_hi + S_lo)
// B=2,H=16,S=2048,D=64 fp32 in/out; bf16 MFMA; S split hi/lo bf16 for precision.

#define S_LEN 2048
#define DHEAD 64
#define CHUNK 64
#define NC    32
#define BH    32
#define LDK   72

typedef float  f32x4  __attribute__((ext_vector_type(4)));
typedef short  bf16x8 __attribute__((ext_vector_type(8)));
typedef unsigned short u16x8 __attribute__((ext_vector_type(8)));

static __device__ __forceinline__ unsigned short f2bf(float f) {
    unsigned int u = __float_as_uint(f);
    u += 0x7FFFu + ((u >> 16) & 1u);
    return (unsigned short)(u >> 16);
}
static __device__ __forceinline__ float bf2f(unsigned short h) {
    return __uint_as_float((unsigned int)h << 16);
}

// ---------------- Phase 1: per-chunk KV summaries U_c (U^T [e][d], fp32) ----------------
__global__ __launch_bounds__(256)
void ret_p1(const float* __restrict__ kg, const float* __restrict__ vg,
            float* __restrict__ Ug) {
    const int c  = (int)blockIdx.x, bh = (int)blockIdx.y, h = bh & 15;
    const int tid = (int)threadIdx.x;
    const int wv = tid >> 6, ln = tid & 63, quad = ln >> 4, lnlo = ln & 15;
    const float sh = log2f(1.0f - exp2f(-5.0f - (float)h));   // < 0

    __shared__ __align__(16) unsigned short Kt[CHUNK * LDK];  // lam-weighted K^T [d][j]
    __shared__ __align__(16) unsigned short Vt[CHUNK * LDK];  // V^T [e][j]

    const size_t cb = (size_t)bh * S_LEN * DHEAD + (size_t)c * CHUNK * DHEAD;
    const float* kp = kg + cb;
    const float* vp = vg + cb;

#pragma unroll
    for (int i = 0; i < 2; ++i) {
        const int pos0 = wv * 8 + i * 32;
        const float* pK = kp + (size_t)pos0 * DHEAD + ln;
        const float* pV = vp + (size_t)pos0 * DHEAD + ln;
        u16x8 tk, tv;
#pragma unroll
        for (int j = 0; j < 8; ++j) {
            const float w = exp2f(sh * (float)(CHUNK - pos0 - j));  // lam^(C - j_local)
            tk[j] = f2bf(pK[(size_t)j * DHEAD] * w);
            tv[j] = f2bf(pV[(size_t)j * DHEAD]);
        }
        *(u16x8*)&Kt[ln * LDK + pos0] = tk;
        *(u16x8*)&Vt[ln * LDK + pos0] = tv;
    }
    __syncthreads();

    bf16x8 aK[2];
#pragma unroll
    for (int ks = 0; ks < 2; ++ks)
        aK[ks] = *(const bf16x8*)&Kt[(wv * 16 + lnlo) * LDK + ks * 32 + quad * 8];

    float* up = Ug + ((size_t)(bh * NC + c) << 12);
#pragma unroll
    for (int nt = 0; nt < 4; ++nt) {
        f32x4 acc = (f32x4){0.f, 0.f, 0.f, 0.f};
#pragma unroll
        for (int ks = 0; ks < 2; ++ks) {
            const bf16x8 bv = *(const bf16x8*)&Vt[(nt * 16 + lnlo) * LDK + ks * 32 + quad * 8];
            acc = __builtin_amdgcn_mfma_f32_16x16x32_bf16(aK[ks], bv, acc, 0, 0, 0);
        }
        // U^T[e][d]: e = nt*16+lnlo, d = wv*16+quad*4+r (contiguous float4)
        *(f32x4*)&up[(nt * 16 + lnlo) * 64 + wv * 16 + quad * 4] = acc;
    }
}

// ---------------- Phase 3: in-block scan + intra + cross ----------------
__global__ __launch_bounds__(256)
void ret_p3(const float* __restrict__ qg, const float* __restrict__ kg,
            const float* __restrict__ vg, const float* __restrict__ Ug,
            float* __restrict__ og) {
    const int c  = (int)blockIdx.x, bh = (int)blockIdx.y, h = bh & 15;
    const int tid = (int)threadIdx.x;
    const int wv = tid >> 6, ln = tid & 63, quad = ln >> 4, lnlo = ln & 15;
    const float sh    = log2f(1.0f - exp2f(-5.0f - (float)h));
    const float scale = 0.125f;

    __shared__ __align__(16) unsigned short Ks[CHUNK * LDK];   // K [pos][d]
    __shared__ __align__(16) unsigned short Vt[CHUNK * LDK];   // V^T [e][pos]
    __shared__ __align__(16) unsigned short ShL[CHUNK * LDK];  // S_hi^T [e][d]; reused as Ws
    __shared__ __align__(16) unsigned short SlL[CHUNK * LDK];  // S_lo^T [e][d]

    const size_t cb = (size_t)bh * S_LEN * DHEAD + (size_t)c * CHUNK * DHEAD;
    const float* qp = qg + cb;
    const float* kp = kg + cb;
    const float* vp = vg + cb;
    float*       op = og + cb;

    // ---- stage K [pos][d] ----
    {
        const int kr = tid >> 2, kc0 = (tid & 3) * 16;
        const float* p = kp + (size_t)kr * DHEAD + kc0;
        const f32x4 x0 = *(const f32x4*)(p + 0);
        const f32x4 x1 = *(const f32x4*)(p + 4);
        const f32x4 x2 = *(const f32x4*)(p + 8);
        const f32x4 x3 = *(const f32x4*)(p + 12);
        u16x8 w0, w1;
        w0[0]=f2bf(x0[0]); w0[1]=f2bf(x0[1]); w0[2]=f2bf(x0[2]); w0[3]=f2bf(x0[3]);
        w0[4]=f2bf(x1[0]); w0[5]=f2bf(x1[1]); w0[6]=f2bf(x1[2]); w0[7]=f2bf(x1[3]);
        w1[0]=f2bf(x2[0]); w1[1]=f2bf(x2[1]); w1[2]=f2bf(x2[2]); w1[3]=f2bf(x2[3]);
        w1[4]=f2bf(x3[0]); w1[5]=f2bf(x3[1]); w1[6]=f2bf(x3[2]); w1[7]=f2bf(x3[3]);
        *(u16x8*)&Ks[kr * LDK + kc0]     = w0;
        *(u16x8*)&Ks[kr * LDK + kc0 + 8] = w1;
    }
    // ---- stage V^T [e][pos] ----
#pragma unroll
    for (int i = 0; i < 2; ++i) {
        const int pos0 = wv * 8 + i * 32;
        const float* p = vp + (size_t)pos0 * DHEAD + ln;
        u16x8 t;
#pragma unroll
        for (int j = 0; j < 8; ++j) t[j] = f2bf(p[(size_t)j * DHEAD]);
        *(u16x8*)&Vt[ln * LDK + pos0] = t;
    }

    // ---- in-block scan: S = sum_{cc<c} lamC^(c-1-cc) * U_cc  (16 elems/thread) ----
    // thread owns flat elems [tid*16, tid*16+16): LDS row r = tid>>2, cols (tid&3)*16..
    {
        float S[16];
#pragma unroll
        for (int i = 0; i < 16; ++i) S[i] = 0.0f;
        const float lamC = exp2f(sh * (float)CHUNK);
        // drop terms with weight < 2^-30 (same bound as rounds 1-3; error << tol)
        const int span  = (int)(30.0f / (CHUNK * (-sh))) + 1;
        const int ccmin = (c - span > 0) ? (c - span) : 0;
        const float* ub = Ug + ((size_t)(bh * NC) << 12) + (size_t)tid * 16;
        float w = 1.0f;
        for (int cc = c - 1; cc >= ccmin; --cc) {
            const float* p = ub + ((size_t)cc << 12);
#pragma unroll
            for (int i = 0; i < 4; ++i) {
                const f32x4 x = *(const f32x4*)(p + i * 4);
                S[i*4+0] += w * x[0]; S[i*4+1] += w * x[1];
                S[i*4+2] += w * x[2]; S[i*4+3] += w * x[3];
            }
            w *= lamC;
        }
        // split hi/lo bf16 into LDS
        const int r = tid >> 2, ccol = (tid & 3) * 16;
        u16x8 hi0, hi1, lo0, lo1;
#pragma unroll
        for (int i = 0; i < 8; ++i) {
            const unsigned short hh = f2bf(S[i]);
            hi0[i] = hh; lo0[i] = f2bf(S[i] - bf2f(hh));
        }
#pragma unroll
        for (int i = 0; i < 8; ++i) {
            const unsigned short hh = f2bf(S[8 + i]);
            hi1[i] = hh; lo1[i] = f2bf(S[8 + i] - bf2f(hh));
        }
        *(u16x8*)&ShL[r * LDK + ccol]     = hi0;
        *(u16x8*)&ShL[r * LDK + ccol + 8] = hi1;
        *(u16x8*)&SlL[r * LDK + ccol]     = lo0;
        *(u16x8*)&SlL[r * LDK + ccol + 8] = lo1;
    }

    // ---- Q A-fragments ----
    bf16x8 aQ[2];
    {
        const float* qrow = qp + (size_t)(wv * 16 + lnlo) * DHEAD;
#pragma unroll
        for (int ks = 0; ks < 2; ++ks) {
            const float* p = qrow + ks * 32 + quad * 8;
            bf16x8 a;
#pragma unroll
            for (int j = 0; j < 8; ++j) a[j] = (short)f2bf(p[j]);
            aQ[ks] = a;
        }
    }
    float rf[4];
#pragma unroll
    for (int r = 0; r < 4; ++r) rf[r] = exp2f((float)(wv * 16 + quad * 4 + r) * sh);

    __syncthreads();

    // ---- cross: o = Q.S_hi + Q.S_lo ----
    f32x4 o[4];
#pragma unroll
    for (int nt = 0; nt < 4; ++nt) {
        f32x4 a = (f32x4){0.f, 0.f, 0.f, 0.f};
#pragma unroll
        for (int ks = 0; ks < 2; ++ks) {
            const bf16x8 bh_ = *(const bf16x8*)&ShL[(nt * 16 + lnlo) * LDK + ks * 32 + quad * 8];
            a = __builtin_amdgcn_mfma_f32_16x16x32_bf16(aQ[ks], bh_, a, 0, 0, 0);
        }
#pragma unroll
        for (int ks = 0; ks < 2; ++ks) {
            const bf16x8 bl_ = *(const bf16x8*)&SlL[(nt * 16 + lnlo) * LDK + ks * 32 + quad * 8];
            a = __builtin_amdgcn_mfma_f32_16x16x32_bf16(aQ[ks], bl_, a, 0, 0, 0);
        }
        o[nt] = a;
    }

    // ---- intra scores ----
    f32x4 acc[4];
#pragma unroll
    for (int nt = 0; nt < 4; ++nt) {
        f32x4 a = (f32x4){0.f, 0.f, 0.f, 0.f};
#pragma unroll
        for (int ks = 0; ks < 2; ++ks) {
            const bf16x8 bk = *(const bf16x8*)&Ks[(nt * 16 + lnlo) * LDK + ks * 32 + quad * 8];
            a = __builtin_amdgcn_mfma_f32_16x16x32_bf16(aQ[ks], bk, a, 0, 0, 0);
        }
        acc[nt] = a;
    }

    // scale cross by scale * lam^(i_local)
#pragma unroll
    for (int nt = 0; nt < 4; ++nt)
#pragma unroll
        for (int r = 0; r < 4; ++r) o[nt][r] *= rf[r] * scale;

    __syncthreads();   // all waves done reading ShL before it becomes Ws

    // ---- decay*scale*causal; C-layout -> A-layout via LDS ----
#pragma unroll
    for (int nt = 0; nt < 4; ++nt) {
        const int jn = nt * 16 + lnlo;
        const float cf = scale * exp2f(-(float)jn * sh);
#pragma unroll
        for (int r = 0; r < 4; ++r) {
            const int ri = wv * 16 + quad * 4 + r;
            float wgt = acc[nt][r] * rf[r] * cf;
            if (ri < jn) wgt = 0.0f;
            ShL[ri * LDK + jn] = f2bf(wgt);
        }
    }
    const bf16x8 aW0 = *(const bf16x8*)&ShL[(wv * 16 + lnlo) * LDK + quad * 8];
    const bf16x8 aW1 = *(const bf16x8*)&ShL[(wv * 16 + lnlo) * LDK + 32 + quad * 8];

    // ---- O += P V ----
#pragma unroll
    for (int nt = 0; nt < 4; ++nt) {
        const bf16x8 bv0 = *(const bf16x8*)&Vt[(nt * 16 + lnlo) * LDK + quad * 8];
        const bf16x8 bv1 = *(const bf16x8*)&Vt[(nt * 16 + lnlo) * LDK + 32 + quad * 8];
        o[nt] = __builtin_amdgcn_mfma_f32_16x16x32_bf16(aW0, bv0, o[nt], 0, 0, 0);
        o[nt] = __builtin_amdgcn_mfma_f32_16x16x32_bf16(aW1, bv1, o[nt], 0, 0, 0);
    }

    // ---- epilogue ----
#pragma unroll
    for (int nt = 0; nt < 4; ++nt)
#pragma unroll
        for (int r = 0; r < 4; ++r)
            op[(size_t)(wv * 16 + quad * 4 + r) * DHEAD + nt * 16 + lnlo] = o[nt][r];
}

extern "C" void kernel_launch(void* const* d_in, const int* in_sizes, int n_in,
                              void* d_out, int out_size, void* d_ws, size_t ws_size,
                              hipStream_t stream) {
    (void)in_sizes; (void)n_in; (void)out_size; (void)ws_size;
    const float* q = (const float*)d_in[0];
    const float* k = (const float*)d_in[1];
    const float* v = (const float*)d_in[2];
    float* o  = (float*)d_out;
    float* Ug = (float*)d_ws;     // 16 MB: [bh][c][e][d] fp32

    dim3 blk(256, 1, 1);
    ret_p1<<<dim3(NC, BH, 1), blk, 0, stream>>>(k, v, Ug);
    ret_p3<<<dim3(NC, BH, 1), blk, 0, stream>>>(q, k, v, Ug, o);
}

// Round 6
// 111.195 us; speedup vs baseline: 4.8497x; 1.2774x over previous
//
#include <hip/hip_runtime.h>

// Retention forward, chunkwise-linear, 3 stream-ordered kernels.
//   p1: U_c[d][e] = sum_j lam^(C-j) K[j][d] V[j][e]   (MFMA, chunks 0..30)
//   p2: S_c = lamC * S_{c-1} + U_{c-1}  (linear elementwise scan, fp32 out)
//   p3: O = intra-chunk + scale*lam^(i_local) * Q.(S_hi + S_lo)
// NOTES (measured): grid.sync ~430us at 1024 blocks (round 4) — never.
// In-block prefix re-scan = quadratic U traffic, +45us (round 5) — never.
// B=2,H=16,S=2048,D=64 fp32 in/out; bf16 MFMA; S split hi/lo bf16 at use site.

#define S_LEN 2048
#define DHEAD 64
#define CHUNK 64
#define NC    32
#define BH    32
#define LDK   72

typedef float  f32x4  __attribute__((ext_vector_type(4)));
typedef short  bf16x8 __attribute__((ext_vector_type(8)));
typedef unsigned short u16x8 __attribute__((ext_vector_type(8)));

static __device__ __forceinline__ unsigned short f2bf(float f) {
    unsigned int u = __float_as_uint(f);
    u += 0x7FFFu + ((u >> 16) & 1u);
    return (unsigned short)(u >> 16);
}
static __device__ __forceinline__ float bf2f(unsigned short h) {
    return __uint_as_float((unsigned int)h << 16);
}

// ---------------- Phase 1: per-chunk KV summaries (U^T [e][d] fp32) ----------------
__global__ __launch_bounds__(256)
void ret_p1(const float* __restrict__ kg, const float* __restrict__ vg,
            float* __restrict__ Ug) {
    const int c  = (int)blockIdx.x, bh = (int)blockIdx.y, h = bh & 15;
    const int tid = (int)threadIdx.x;
    const int wv = tid >> 6, ln = tid & 63, quad = ln >> 4, lnlo = ln & 15;
    const float sh = log2f(1.0f - exp2f(-5.0f - (float)h));   // < 0

    __shared__ __align__(16) unsigned short Kt[CHUNK * LDK];  // lam-weighted K^T [d][j]
    __shared__ __align__(16) unsigned short Vt[CHUNK * LDK];  // V^T [e][j]

    const size_t cb = (size_t)bh * S_LEN * DHEAD + (size_t)c * CHUNK * DHEAD;
    const float* kp = kg + cb;
    const float* vp = vg + cb;

#pragma unroll
    for (int i = 0; i < 2; ++i) {
        const int pos0 = wv * 8 + i * 32;
        const float* pK = kp + (size_t)pos0 * DHEAD + ln;
        const float* pV = vp + (size_t)pos0 * DHEAD + ln;
        u16x8 tk, tv;
#pragma unroll
        for (int j = 0; j < 8; ++j) {
            const float w = exp2f(sh * (float)(CHUNK - pos0 - j));  // lam^(C - j_local)
            tk[j] = f2bf(pK[(size_t)j * DHEAD] * w);
            tv[j] = f2bf(pV[(size_t)j * DHEAD]);
        }
        *(u16x8*)&Kt[ln * LDK + pos0] = tk;
        *(u16x8*)&Vt[ln * LDK + pos0] = tv;
    }
    __syncthreads();

    bf16x8 aK[2];
#pragma unroll
    for (int ks = 0; ks < 2; ++ks)
        aK[ks] = *(const bf16x8*)&Kt[(wv * 16 + lnlo) * LDK + ks * 32 + quad * 8];

    float* up = Ug + ((size_t)(bh * NC + c) << 12);
#pragma unroll
    for (int nt = 0; nt < 4; ++nt) {
        f32x4 acc = (f32x4){0.f, 0.f, 0.f, 0.f};
#pragma unroll
        for (int ks = 0; ks < 2; ++ks) {
            const bf16x8 bv = *(const bf16x8*)&Vt[(nt * 16 + lnlo) * LDK + ks * 32 + quad * 8];
            acc = __builtin_amdgcn_mfma_f32_16x16x32_bf16(aK[ks], bv, acc, 0, 0, 0);
        }
        // U^T[e][d]: e = nt*16+lnlo, d = wv*16+quad*4+r
        *(f32x4*)&up[(nt * 16 + lnlo) * 64 + wv * 16 + quad * 4] = acc;
    }
}

// ---------------- Phase 2: linear scan, fp32 S out ----------------
__global__ __launch_bounds__(256)
void ret_p2(const float* __restrict__ Ug, float* __restrict__ Sg) {
    const int eb = (int)blockIdx.x, bh = (int)blockIdx.y, h = bh & 15;
    const float sh   = log2f(1.0f - exp2f(-5.0f - (float)h));
    const float lamC = exp2f(sh * (float)CHUNK);
    const int elem = eb * 256 + (int)threadIdx.x;

    const float* up = Ug + ((size_t)(bh * NC) << 12) + elem;
    float*       sp = Sg + ((size_t)(bh * NC) << 12) + elem;

    float S = 0.0f;
    float u = up[0];
    for (int c = 0; c < NC; ++c) {
        const float un = (c + 1 < NC - 1) ? up[(size_t)(c + 1) << 12] : 0.0f;  // U_31 unused
        sp[(size_t)c << 12] = S;
        S = lamC * S + u;
        u = un;
    }
}

// ---------------- Phase 3: intra + cross ----------------
__global__ __launch_bounds__(256)
void ret_p3(const float* __restrict__ qg, const float* __restrict__ kg,
            const float* __restrict__ vg, const float* __restrict__ Sg,
            float* __restrict__ og) {
    const int c  = (int)blockIdx.x, bh = (int)blockIdx.y, h = bh & 15;
    const int tid = (int)threadIdx.x;
    const int wv = tid >> 6, ln = tid & 63, quad = ln >> 4, lnlo = ln & 15;
    const float sh    = log2f(1.0f - exp2f(-5.0f - (float)h));
    const float scale = 0.125f;

    __shared__ __align__(16) unsigned short Ks[CHUNK * LDK];   // K [pos][d]
    __shared__ __align__(16) unsigned short Vt[CHUNK * LDK];   // V^T [e][pos]
    __shared__ __align__(16) unsigned short ShL[CHUNK * LDK];  // S_hi^T [e][d]; reused as Ws
    __shared__ __align__(16) unsigned short SlL[CHUNK * LDK];  // S_lo^T [e][d]

    const size_t cb = (size_t)bh * S_LEN * DHEAD + (size_t)c * CHUNK * DHEAD;
    const float* qp = qg + cb;
    const float* kp = kg + cb;
    const float* vp = vg + cb;
    float*       op = og + cb;

    // ---- stage K [pos][d] ----
    {
        const int kr = tid >> 2, kc0 = (tid & 3) * 16;
        const float* p = kp + (size_t)kr * DHEAD + kc0;
        const f32x4 x0 = *(const f32x4*)(p + 0);
        const f32x4 x1 = *(const f32x4*)(p + 4);
        const f32x4 x2 = *(const f32x4*)(p + 8);
        const f32x4 x3 = *(const f32x4*)(p + 12);
        u16x8 w0, w1;
        w0[0]=f2bf(x0[0]); w0[1]=f2bf(x0[1]); w0[2]=f2bf(x0[2]); w0[3]=f2bf(x0[3]);
        w0[4]=f2bf(x1[0]); w0[5]=f2bf(x1[1]); w0[6]=f2bf(x1[2]); w0[7]=f2bf(x1[3]);
        w1[0]=f2bf(x2[0]); w1[1]=f2bf(x2[1]); w1[2]=f2bf(x2[2]); w1[3]=f2bf(x2[3]);
        w1[4]=f2bf(x3[0]); w1[5]=f2bf(x3[1]); w1[6]=f2bf(x3[2]); w1[7]=f2bf(x3[3]);
        *(u16x8*)&Ks[kr * LDK + kc0]     = w0;
        *(u16x8*)&Ks[kr * LDK + kc0 + 8] = w1;
    }
    // ---- stage V^T [e][pos] ----
#pragma unroll
    for (int i = 0; i < 2; ++i) {
        const int pos0 = wv * 8 + i * 32;
        const float* p = vp + (size_t)pos0 * DHEAD + ln;
        u16x8 t;
#pragma unroll
        for (int j = 0; j < 8; ++j) t[j] = f2bf(p[(size_t)j * DHEAD]);
        *(u16x8*)&Vt[ln * LDK + pos0] = t;
    }
    // ---- stage S chunk (16 KB coalesced fp32), split hi/lo bf16 into LDS ----
    {
        const float* sp = Sg + ((size_t)(bh * NC + c) << 12) + (size_t)tid * 16;
        const int r = tid >> 2, ccol = (tid & 3) * 16;
        u16x8 hi0, hi1, lo0, lo1;
#pragma unroll
        for (int i = 0; i < 2; ++i) {
            const f32x4 x0 = *(const f32x4*)(sp + i * 8);
            const f32x4 x1 = *(const f32x4*)(sp + i * 8 + 4);
            u16x8 hi, lo;
#pragma unroll
            for (int j = 0; j < 4; ++j) {
                const unsigned short hh = f2bf(x0[j]);
                hi[j] = hh; lo[j] = f2bf(x0[j] - bf2f(hh));
            }
#pragma unroll
            for (int j = 0; j < 4; ++j) {
                const unsigned short hh = f2bf(x1[j]);
                hi[4 + j] = hh; lo[4 + j] = f2bf(x1[j] - bf2f(hh));
            }
            if (i == 0) { hi0 = hi; lo0 = lo; } else { hi1 = hi; lo1 = lo; }
        }
        *(u16x8*)&ShL[r * LDK + ccol]     = hi0;
        *(u16x8*)&ShL[r * LDK + ccol + 8] = hi1;
        *(u16x8*)&SlL[r * LDK + ccol]     = lo0;
        *(u16x8*)&SlL[r * LDK + ccol + 8] = lo1;
    }

    // ---- Q A-fragments ----
    bf16x8 aQ[2];
    {
        const float* qrow = qp + (size_t)(wv * 16 + lnlo) * DHEAD;
#pragma unroll
        for (int ks = 0; ks < 2; ++ks) {
            const float* p = qrow + ks * 32 + quad * 8;
            bf16x8 a;
#pragma unroll
            for (int j = 0; j < 8; ++j) a[j] = (short)f2bf(p[j]);
            aQ[ks] = a;
        }
    }
    float rf[4];
#pragma unroll
    for (int r = 0; r < 4; ++r) rf[r] = exp2f((float)(wv * 16 + quad * 4 + r) * sh);

    __syncthreads();

    // ---- cross: o = Q.S_hi + Q.S_lo ----
    f32x4 o[4];
#pragma unroll
    for (int nt = 0; nt < 4; ++nt) {
        f32x4 a = (f32x4){0.f, 0.f, 0.f, 0.f};
#pragma unroll
        for (int ks = 0; ks < 2; ++ks) {
            const bf16x8 bh_ = *(const bf16x8*)&ShL[(nt * 16 + lnlo) * LDK + ks * 32 + quad * 8];
            a = __builtin_amdgcn_mfma_f32_16x16x32_bf16(aQ[ks], bh_, a, 0, 0, 0);
        }
#pragma unroll
        for (int ks = 0; ks < 2; ++ks) {
            const bf16x8 bl_ = *(const bf16x8*)&SlL[(nt * 16 + lnlo) * LDK + ks * 32 + quad * 8];
            a = __builtin_amdgcn_mfma_f32_16x16x32_bf16(aQ[ks], bl_, a, 0, 0, 0);
        }
        o[nt] = a;
    }

    // ---- intra scores ----
    f32x4 acc[4];
#pragma unroll
    for (int nt = 0; nt < 4; ++nt) {
        f32x4 a = (f32x4){0.f, 0.f, 0.f, 0.f};
#pragma unroll
        for (int ks = 0; ks < 2; ++ks) {
            const bf16x8 bk = *(const bf16x8*)&Ks[(nt * 16 + lnlo) * LDK + ks * 32 + quad * 8];
            a = __builtin_amdgcn_mfma_f32_16x16x32_bf16(aQ[ks], bk, a, 0, 0, 0);
        }
        acc[nt] = a;
    }

    // scale cross by scale * lam^(i_local)
#pragma unroll
    for (int nt = 0; nt < 4; ++nt)
#pragma unroll
        for (int r = 0; r < 4; ++r) o[nt][r] *= rf[r] * scale;

    __syncthreads();   // all waves done reading ShL before it becomes Ws

    // ---- decay*scale*causal; C-layout -> A-layout via LDS ----
#pragma unroll
    for (int nt = 0; nt < 4; ++nt) {
        const int jn = nt * 16 + lnlo;
        const float cf = scale * exp2f(-(float)jn * sh);
#pragma unroll
        for (int r = 0; r < 4; ++r) {
            const int ri = wv * 16 + quad * 4 + r;
            float wgt = acc[nt][r] * rf[r] * cf;
            if (ri < jn) wgt = 0.0f;
            ShL[ri * LDK + jn] = f2bf(wgt);
        }
    }
    const bf16x8 aW0 = *(const bf16x8*)&ShL[(wv * 16 + lnlo) * LDK + quad * 8];
    const bf16x8 aW1 = *(const bf16x8*)&ShL[(wv * 16 + lnlo) * LDK + 32 + quad * 8];

    // ---- O += P V ----
#pragma unroll
    for (int nt = 0; nt < 4; ++nt) {
        const bf16x8 bv0 = *(const bf16x8*)&Vt[(nt * 16 + lnlo) * LDK + quad * 8];
        const bf16x8 bv1 = *(const bf16x8*)&Vt[(nt * 16 + lnlo) * LDK + 32 + quad * 8];
        o[nt] = __builtin_amdgcn_mfma_f32_16x16x32_bf16(aW0, bv0, o[nt], 0, 0, 0);
        o[nt] = __builtin_amdgcn_mfma_f32_16x16x32_bf16(aW1, bv1, o[nt], 0, 0, 0);
    }

    // ---- epilogue ----
#pragma unroll
    for (int nt = 0; nt < 4; ++nt)
#pragma unroll
        for (int r = 0; r < 4; ++r)
            op[(size_t)(wv * 16 + quad * 4 + r) * DHEAD + nt * 16 + lnlo] = o[nt][r];
}

extern "C" void kernel_launch(void* const* d_in, const int* in_sizes, int n_in,
                              void* d_out, int out_size, void* d_ws, size_t ws_size,
                              hipStream_t stream) {
    (void)in_sizes; (void)n_in; (void)out_size; (void)ws_size;
    const float* q = (const float*)d_in[0];
    const float* k = (const float*)d_in[1];
    const float* v = (const float*)d_in[2];
    float* o  = (float*)d_out;
    float* Ug = (float*)d_ws;                            // 16 MB [bh][c][e*64+d]
    float* Sg = (float*)((char*)d_ws + (size_t)BH * NC * 4096 * 4);  // 16 MB

    dim3 blk(256, 1, 1);
    ret_p1<<<dim3(NC - 1, BH, 1), blk, 0, stream>>>(k, v, Ug);   // U_31 never consumed
    ret_p2<<<dim3(16, BH, 1), blk, 0, stream>>>(Ug, Sg);
    ret_p3<<<dim3(NC, BH, 1), blk, 0, stream>>>(q, k, v, Sg, o);
}

// Round 7
// 106.459 us; speedup vs baseline: 5.0654x; 1.0445x over previous
//
#include <hip/hip_runtime.h>

// Retention forward, chunkwise-linear, 3 stream-ordered kernels.
//   p1: U_c[d][e] = sum_j lam^(C-j) K[j][d] V[j][e]   (MFMA, chunks 0..30)
//   p2: S_c = lamC * S_{c-1} + U_{c-1}  (linear elementwise scan) -> bf16 S
//   p3: O = intra-chunk + scale*lam^(i_local) * Q.S
// Measured design rules: grid.sync ~430us @1024 blocks (r4) — never.
// Per-block prefix re-scan = quadratic U traffic (+45us, r5) — never.
// S as single bf16 (r7): adds <=~0.3 absmax vs 4.46 threshold; saves 16 MB
// round-trip + halves cross MFMAs in p3.

#define S_LEN 2048
#define DHEAD 64
#define CHUNK 64
#define NC    32
#define BH    32
#define LDK   72

typedef float  f32x4  __attribute__((ext_vector_type(4)));
typedef short  bf16x8 __attribute__((ext_vector_type(8)));
typedef unsigned short u16x8 __attribute__((ext_vector_type(8)));

static __device__ __forceinline__ unsigned short f2bf(float f) {
    unsigned int u = __float_as_uint(f);
    u += 0x7FFFu + ((u >> 16) & 1u);
    return (unsigned short)(u >> 16);
}

// ---------------- Phase 1: per-chunk KV summaries (U^T [e][d] fp32) ----------------
__global__ __launch_bounds__(256)
void ret_p1(const float* __restrict__ kg, const float* __restrict__ vg,
            float* __restrict__ Ug) {
    const int c  = (int)blockIdx.x, bh = (int)blockIdx.y, h = bh & 15;
    const int tid = (int)threadIdx.x;
    const int wv = tid >> 6, ln = tid & 63, quad = ln >> 4, lnlo = ln & 15;
    const float sh = log2f(1.0f - exp2f(-5.0f - (float)h));   // < 0

    __shared__ __align__(16) unsigned short Kt[CHUNK * LDK];  // lam-weighted K^T [d][j]
    __shared__ __align__(16) unsigned short Vt[CHUNK * LDK];  // V^T [e][j]

    const size_t cb = (size_t)bh * S_LEN * DHEAD + (size_t)c * CHUNK * DHEAD;
    const float* kp = kg + cb;
    const float* vp = vg + cb;

#pragma unroll
    for (int i = 0; i < 2; ++i) {
        const int pos0 = wv * 8 + i * 32;
        const float* pK = kp + (size_t)pos0 * DHEAD + ln;
        const float* pV = vp + (size_t)pos0 * DHEAD + ln;
        u16x8 tk, tv;
#pragma unroll
        for (int j = 0; j < 8; ++j) {
            const float w = exp2f(sh * (float)(CHUNK - pos0 - j));  // lam^(C - j_local)
            tk[j] = f2bf(pK[(size_t)j * DHEAD] * w);
            tv[j] = f2bf(pV[(size_t)j * DHEAD]);
        }
        *(u16x8*)&Kt[ln * LDK + pos0] = tk;
        *(u16x8*)&Vt[ln * LDK + pos0] = tv;
    }
    __syncthreads();

    bf16x8 aK[2];
#pragma unroll
    for (int ks = 0; ks < 2; ++ks)
        aK[ks] = *(const bf16x8*)&Kt[(wv * 16 + lnlo) * LDK + ks * 32 + quad * 8];

    float* up = Ug + ((size_t)(bh * NC + c) << 12);
#pragma unroll
    for (int nt = 0; nt < 4; ++nt) {
        f32x4 acc = (f32x4){0.f, 0.f, 0.f, 0.f};
#pragma unroll
        for (int ks = 0; ks < 2; ++ks) {
            const bf16x8 bv = *(const bf16x8*)&Vt[(nt * 16 + lnlo) * LDK + ks * 32 + quad * 8];
            acc = __builtin_amdgcn_mfma_f32_16x16x32_bf16(aK[ks], bv, acc, 0, 0, 0);
        }
        // U^T[e][d]: e = nt*16+lnlo, d = wv*16+quad*4+r
        *(f32x4*)&up[(nt * 16 + lnlo) * 64 + wv * 16 + quad * 4] = acc;
    }
}

// ---------------- Phase 2: linear scan, bf16 S out ----------------
__global__ __launch_bounds__(256)
void ret_p2(const float* __restrict__ Ug, unsigned short* __restrict__ Sg) {
    const int eb = (int)blockIdx.x, bh = (int)blockIdx.y, h = bh & 15;
    const float sh   = log2f(1.0f - exp2f(-5.0f - (float)h));
    const float lamC = exp2f(sh * (float)CHUNK);
    const int elem = eb * 256 + (int)threadIdx.x;

    const float*    up = Ug + ((size_t)(bh * NC) << 12) + elem;
    unsigned short* sp = Sg + ((size_t)(bh * NC) << 12) + elem;

    float S = 0.0f;
    float u = up[0];
    for (int c = 0; c < NC; ++c) {
        const float un = (c + 1 < NC - 1) ? up[(size_t)(c + 1) << 12] : 0.0f;  // U_31 unused
        sp[(size_t)c << 12] = f2bf(S);
        S = lamC * S + u;
        u = un;
    }
}

// ---------------- Phase 3: intra + cross ----------------
__global__ __launch_bounds__(256)
void ret_p3(const float* __restrict__ qg, const float* __restrict__ kg,
            const float* __restrict__ vg, const unsigned short* __restrict__ Sg,
            float* __restrict__ og) {
    const int c  = (int)blockIdx.x, bh = (int)blockIdx.y, h = bh & 15;
    const int tid = (int)threadIdx.x;
    const int wv = tid >> 6, ln = tid & 63, quad = ln >> 4, lnlo = ln & 15;
    const float sh    = log2f(1.0f - exp2f(-5.0f - (float)h));
    const float scale = 0.125f;

    __shared__ __align__(16) unsigned short Ks[CHUNK * LDK];   // K [pos][d]
    __shared__ __align__(16) unsigned short Vt[CHUNK * LDK];   // V^T [e][pos]
    __shared__ __align__(16) unsigned short ShL[CHUNK * LDK];  // S^T [e][d]; reused as Ws

    const size_t cb = (size_t)bh * S_LEN * DHEAD + (size_t)c * CHUNK * DHEAD;
    const float* qp = qg + cb;
    const float* kp = kg + cb;
    const float* vp = vg + cb;
    float*       op = og + cb;

    // ---- stage K [pos][d] ----
    {
        const int kr = tid >> 2, kc0 = (tid & 3) * 16;
        const float* p = kp + (size_t)kr * DHEAD + kc0;
        const f32x4 x0 = *(const f32x4*)(p + 0);
        const f32x4 x1 = *(const f32x4*)(p + 4);
        const f32x4 x2 = *(const f32x4*)(p + 8);
        const f32x4 x3 = *(const f32x4*)(p + 12);
        u16x8 w0, w1;
        w0[0]=f2bf(x0[0]); w0[1]=f2bf(x0[1]); w0[2]=f2bf(x0[2]); w0[3]=f2bf(x0[3]);
        w0[4]=f2bf(x1[0]); w0[5]=f2bf(x1[1]); w0[6]=f2bf(x1[2]); w0[7]=f2bf(x1[3]);
        w1[0]=f2bf(x2[0]); w1[1]=f2bf(x2[1]); w1[2]=f2bf(x2[2]); w1[3]=f2bf(x2[3]);
        w1[4]=f2bf(x3[0]); w1[5]=f2bf(x3[1]); w1[6]=f2bf(x3[2]); w1[7]=f2bf(x3[3]);
        *(u16x8*)&Ks[kr * LDK + kc0]     = w0;
        *(u16x8*)&Ks[kr * LDK + kc0 + 8] = w1;
    }
    // ---- stage V^T [e][pos] ----
#pragma unroll
    for (int i = 0; i < 2; ++i) {
        const int pos0 = wv * 8 + i * 32;
        const float* p = vp + (size_t)pos0 * DHEAD + ln;
        u16x8 t;
#pragma unroll
        for (int j = 0; j < 8; ++j) t[j] = f2bf(p[(size_t)j * DHEAD]);
        *(u16x8*)&Vt[ln * LDK + pos0] = t;
    }
    // ---- stage S^T chunk (8 KB bf16, straight coalesced copy) ----
    {
        const size_t sb = ((size_t)(bh * NC + c) << 12) + (size_t)tid * 16;
        const int r = tid >> 2, ccol = (tid & 3) * 16;
        *(u16x8*)&ShL[r * LDK + ccol]     = *(const u16x8*)(Sg + sb);
        *(u16x8*)&ShL[r * LDK + ccol + 8] = *(const u16x8*)(Sg + sb + 8);
    }

    // ---- Q A-fragments ----
    bf16x8 aQ[2];
    {
        const float* qrow = qp + (size_t)(wv * 16 + lnlo) * DHEAD;
#pragma unroll
        for (int ks = 0; ks < 2; ++ks) {
            const float* p = qrow + ks * 32 + quad * 8;
            bf16x8 a;
#pragma unroll
            for (int j = 0; j < 8; ++j) a[j] = (short)f2bf(p[j]);
            aQ[ks] = a;
        }
    }
    float rf[4];
#pragma unroll
    for (int r = 0; r < 4; ++r) rf[r] = exp2f((float)(wv * 16 + quad * 4 + r) * sh);

    __syncthreads();

    // ---- cross: o = Q.S ----
    f32x4 o[4];
#pragma unroll
    for (int nt = 0; nt < 4; ++nt) {
        f32x4 a = (f32x4){0.f, 0.f, 0.f, 0.f};
#pragma unroll
        for (int ks = 0; ks < 2; ++ks) {
            const bf16x8 bs = *(const bf16x8*)&ShL[(nt * 16 + lnlo) * LDK + ks * 32 + quad * 8];
            a = __builtin_amdgcn_mfma_f32_16x16x32_bf16(aQ[ks], bs, a, 0, 0, 0);
        }
        o[nt] = a;
    }

    // ---- intra scores ----
    f32x4 acc[4];
#pragma unroll
    for (int nt = 0; nt < 4; ++nt) {
        f32x4 a = (f32x4){0.f, 0.f, 0.f, 0.f};
#pragma unroll
        for (int ks = 0; ks < 2; ++ks) {
            const bf16x8 bk = *(const bf16x8*)&Ks[(nt * 16 + lnlo) * LDK + ks * 32 + quad * 8];
            a = __builtin_amdgcn_mfma_f32_16x16x32_bf16(aQ[ks], bk, a, 0, 0, 0);
        }
        acc[nt] = a;
    }

    // scale cross by scale * lam^(i_local)
#pragma unroll
    for (int nt = 0; nt < 4; ++nt)
#pragma unroll
        for (int r = 0; r < 4; ++r) o[nt][r] *= rf[r] * scale;

    __syncthreads();   // all waves done reading ShL before it becomes Ws

    // ---- decay*scale*causal; C-layout -> A-layout via LDS ----
#pragma unroll
    for (int nt = 0; nt < 4; ++nt) {
        const int jn = nt * 16 + lnlo;
        const float cf = scale * exp2f(-(float)jn * sh);
#pragma unroll
        for (int r = 0; r < 4; ++r) {
            const int ri = wv * 16 + quad * 4 + r;
            float wgt = acc[nt][r] * rf[r] * cf;
            if (ri < jn) wgt = 0.0f;
            ShL[ri * LDK + jn] = f2bf(wgt);
        }
    }
    const bf16x8 aW0 = *(const bf16x8*)&ShL[(wv * 16 + lnlo) * LDK + quad * 8];
    const bf16x8 aW1 = *(const bf16x8*)&ShL[(wv * 16 + lnlo) * LDK + 32 + quad * 8];

    // ---- O += P V ----
#pragma unroll
    for (int nt = 0; nt < 4; ++nt) {
        const bf16x8 bv0 = *(const bf16x8*)&Vt[(nt * 16 + lnlo) * LDK + quad * 8];
        const bf16x8 bv1 = *(const bf16x8*)&Vt[(nt * 16 + lnlo) * LDK + 32 + quad * 8];
        o[nt] = __builtin_amdgcn_mfma_f32_16x16x32_bf16(aW0, bv0, o[nt], 0, 0, 0);
        o[nt] = __builtin_amdgcn_mfma_f32_16x16x32_bf16(aW1, bv1, o[nt], 0, 0, 0);
    }

    // ---- epilogue ----
#pragma unroll
    for (int nt = 0; nt < 4; ++nt)
#pragma unroll
        for (int r = 0; r < 4; ++r)
            op[(size_t)(wv * 16 + quad * 4 + r) * DHEAD + nt * 16 + lnlo] = o[nt][r];
}

extern "C" void kernel_launch(void* const* d_in, const int* in_sizes, int n_in,
                              void* d_out, int out_size, void* d_ws, size_t ws_size,
                              hipStream_t stream) {
    (void)in_sizes; (void)n_in; (void)out_size; (void)ws_size;
    const float* q = (const float*)d_in[0];
    const float* k = (const float*)d_in[1];
    const float* v = (const float*)d_in[2];
    float* o  = (float*)d_out;
    float*          Ug = (float*)d_ws;                                      // 16 MB fp32
    unsigned short* Sg = (unsigned short*)((char*)d_ws + (size_t)BH * NC * 4096 * 4);  // 8 MB bf16

    dim3 blk(256, 1, 1);
    ret_p1<<<dim3(NC - 1, BH, 1), blk, 0, stream>>>(k, v, Ug);   // U_31 never consumed
    ret_p2<<<dim3(16, BH, 1), blk, 0, stream>>>(Ug, Sg);
    ret_p3<<<dim3(NC, BH, 1), blk, 0, stream>>>(q, k, v, Sg, o);
}

// Round 8
// 104.893 us; speedup vs baseline: 5.1411x; 1.0149x over previous
//
#include <hip/hip_runtime.h>

// Retention forward, chunkwise-linear, 3 stream-ordered kernels.
//   p1: U_c[d][e] = sum_j lam^(C-j) K[j][d] V[j][e]   (MFMA, chunks 0..30) -> bf16
//   p2: S_c = lamC * S_{c-1} + U_{c-1}  (linear elementwise scan) -> bf16 S
//   p3: O = intra-chunk + scale*lam^(i_local) * Q.S
// Measured design rules: grid.sync ~430us @1024 blocks (r4) — never.
// Per-block prefix re-scan = quadratic U traffic (+45us, r5) — never.
// bf16 S (r7, +0 absmax) and bf16 U (r8): intermediates well inside the
// bf16-grade tolerance (threshold 4.46, measured absmax 1.0).

#define S_LEN 2048
#define DHEAD 64
#define CHUNK 64
#define NC    32
#define BH    32
#define LDK   72

typedef float  f32x4  __attribute__((ext_vector_type(4)));
typedef short  bf16x8 __attribute__((ext_vector_type(8)));
typedef unsigned short u16x8 __attribute__((ext_vector_type(8)));
typedef unsigned short u16x4 __attribute__((ext_vector_type(4)));

static __device__ __forceinline__ unsigned short f2bf(float f) {
    unsigned int u = __float_as_uint(f);
    u += 0x7FFFu + ((u >> 16) & 1u);
    return (unsigned short)(u >> 16);
}
static __device__ __forceinline__ float bf2f(unsigned short h) {
    return __uint_as_float((unsigned int)h << 16);
}

// ---------------- Phase 1: per-chunk KV summaries (U^T [e][d] bf16) ----------------
__global__ __launch_bounds__(256)
void ret_p1(const float* __restrict__ kg, const float* __restrict__ vg,
            unsigned short* __restrict__ Ug) {
    const int c  = (int)blockIdx.x, bh = (int)blockIdx.y, h = bh & 15;
    const int tid = (int)threadIdx.x;
    const int wv = tid >> 6, ln = tid & 63, quad = ln >> 4, lnlo = ln & 15;
    const float sh = log2f(1.0f - exp2f(-5.0f - (float)h));   // < 0

    __shared__ __align__(16) unsigned short Kt[CHUNK * LDK];  // lam-weighted K^T [d][j]
    __shared__ __align__(16) unsigned short Vt[CHUNK * LDK];  // V^T [e][j]

    const size_t cb = (size_t)bh * S_LEN * DHEAD + (size_t)c * CHUNK * DHEAD;
    const float* kp = kg + cb;
    const float* vp = vg + cb;

#pragma unroll
    for (int i = 0; i < 2; ++i) {
        const int pos0 = wv * 8 + i * 32;
        const float* pK = kp + (size_t)pos0 * DHEAD + ln;
        const float* pV = vp + (size_t)pos0 * DHEAD + ln;
        u16x8 tk, tv;
#pragma unroll
        for (int j = 0; j < 8; ++j) {
            const float w = exp2f(sh * (float)(CHUNK - pos0 - j));  // lam^(C - j_local)
            tk[j] = f2bf(pK[(size_t)j * DHEAD] * w);
            tv[j] = f2bf(pV[(size_t)j * DHEAD]);
        }
        *(u16x8*)&Kt[ln * LDK + pos0] = tk;
        *(u16x8*)&Vt[ln * LDK + pos0] = tv;
    }
    __syncthreads();

    bf16x8 aK[2];
#pragma unroll
    for (int ks = 0; ks < 2; ++ks)
        aK[ks] = *(const bf16x8*)&Kt[(wv * 16 + lnlo) * LDK + ks * 32 + quad * 8];

    unsigned short* up = Ug + ((size_t)(bh * NC + c) << 12);
#pragma unroll
    for (int nt = 0; nt < 4; ++nt) {
        f32x4 acc = (f32x4){0.f, 0.f, 0.f, 0.f};
#pragma unroll
        for (int ks = 0; ks < 2; ++ks) {
            const bf16x8 bv = *(const bf16x8*)&Vt[(nt * 16 + lnlo) * LDK + ks * 32 + quad * 8];
            acc = __builtin_amdgcn_mfma_f32_16x16x32_bf16(aK[ks], bv, acc, 0, 0, 0);
        }
        // U^T[e][d]: e = nt*16+lnlo, d = wv*16+quad*4+r  (8B store per lane)
        u16x4 w;
#pragma unroll
        for (int r = 0; r < 4; ++r) w[r] = f2bf(acc[r]);
        *(u16x4*)&up[(nt * 16 + lnlo) * 64 + wv * 16 + quad * 4] = w;
    }
}

// ---------------- Phase 2: linear scan (bf16 U in, bf16 S out) ----------------
__global__ __launch_bounds__(256)
void ret_p2(const unsigned short* __restrict__ Ug, unsigned short* __restrict__ Sg) {
    const int eb = (int)blockIdx.x, bh = (int)blockIdx.y, h = bh & 15;
    const float sh   = log2f(1.0f - exp2f(-5.0f - (float)h));
    const float lamC = exp2f(sh * (float)CHUNK);
    const int elem = eb * 256 + (int)threadIdx.x;

    const unsigned short* up = Ug + ((size_t)(bh * NC) << 12) + elem;
    unsigned short*       sp = Sg + ((size_t)(bh * NC) << 12) + elem;

    float S = 0.0f;
    float u = bf2f(up[0]);
    for (int c = 0; c < NC; ++c) {
        const float un = (c + 1 < NC - 1) ? bf2f(up[(size_t)(c + 1) << 12]) : 0.0f;  // U_31 unused
        sp[(size_t)c << 12] = f2bf(S);
        S = lamC * S + u;
        u = un;
    }
}

// ---------------- Phase 3: intra + cross ----------------
__global__ __launch_bounds__(256)
void ret_p3(const float* __restrict__ qg, const float* __restrict__ kg,
            const float* __restrict__ vg, const unsigned short* __restrict__ Sg,
            float* __restrict__ og) {
    const int c  = (int)blockIdx.x, bh = (int)blockIdx.y, h = bh & 15;
    const int tid = (int)threadIdx.x;
    const int wv = tid >> 6, ln = tid & 63, quad = ln >> 4, lnlo = ln & 15;
    const float sh    = log2f(1.0f - exp2f(-5.0f - (float)h));
    const float scale = 0.125f;

    __shared__ __align__(16) unsigned short Ks[CHUNK * LDK];   // K [pos][d]
    __shared__ __align__(16) unsigned short Vt[CHUNK * LDK];   // V^T [e][pos]
    __shared__ __align__(16) unsigned short ShL[CHUNK * LDK];  // S^T [e][d]; reused as Ws

    const size_t cb = (size_t)bh * S_LEN * DHEAD + (size_t)c * CHUNK * DHEAD;
    const float* qp = qg + cb;
    const float* kp = kg + cb;
    const float* vp = vg + cb;
    float*       op = og + cb;

    // ---- stage K [pos][d] ----
    {
        const int kr = tid >> 2, kc0 = (tid & 3) * 16;
        const float* p = kp + (size_t)kr * DHEAD + kc0;
        const f32x4 x0 = *(const f32x4*)(p + 0);
        const f32x4 x1 = *(const f32x4*)(p + 4);
        const f32x4 x2 = *(const f32x4*)(p + 8);
        const f32x4 x3 = *(const f32x4*)(p + 12);
        u16x8 w0, w1;
        w0[0]=f2bf(x0[0]); w0[1]=f2bf(x0[1]); w0[2]=f2bf(x0[2]); w0[3]=f2bf(x0[3]);
        w0[4]=f2bf(x1[0]); w0[5]=f2bf(x1[1]); w0[6]=f2bf(x1[2]); w0[7]=f2bf(x1[3]);
        w1[0]=f2bf(x2[0]); w1[1]=f2bf(x2[1]); w1[2]=f2bf(x2[2]); w1[3]=f2bf(x2[3]);
        w1[4]=f2bf(x3[0]); w1[5]=f2bf(x3[1]); w1[6]=f2bf(x3[2]); w1[7]=f2bf(x3[3]);
        *(u16x8*)&Ks[kr * LDK + kc0]     = w0;
        *(u16x8*)&Ks[kr * LDK + kc0 + 8] = w1;
    }
    // ---- stage V^T [e][pos] ----
#pragma unroll
    for (int i = 0; i < 2; ++i) {
        const int pos0 = wv * 8 + i * 32;
        const float* p = vp + (size_t)pos0 * DHEAD + ln;
        u16x8 t;
#pragma unroll
        for (int j = 0; j < 8; ++j) t[j] = f2bf(p[(size_t)j * DHEAD]);
        *(u16x8*)&Vt[ln * LDK + pos0] = t;
    }
    // ---- stage S^T chunk (8 KB bf16, straight coalesced copy) ----
    {
        const size_t sb = ((size_t)(bh * NC + c) << 12) + (size_t)tid * 16;
        const int r = tid >> 2, ccol = (tid & 3) * 16;
        *(u16x8*)&ShL[r * LDK + ccol]     = *(const u16x8*)(Sg + sb);
        *(u16x8*)&ShL[r * LDK + ccol + 8] = *(const u16x8*)(Sg + sb + 8);
    }

    // ---- Q A-fragments ----
    bf16x8 aQ[2];
    {
        const float* qrow = qp + (size_t)(wv * 16 + lnlo) * DHEAD;
#pragma unroll
        for (int ks = 0; ks < 2; ++ks) {
            const float* p = qrow + ks * 32 + quad * 8;
            bf16x8 a;
#pragma unroll
            for (int j = 0; j < 8; ++j) a[j] = (short)f2bf(p[j]);
            aQ[ks] = a;
        }
    }
    float rf[4];
#pragma unroll
    for (int r = 0; r < 4; ++r) rf[r] = exp2f((float)(wv * 16 + quad * 4 + r) * sh);

    __syncthreads();

    // ---- cross: o = Q.S ----
    f32x4 o[4];
#pragma unroll
    for (int nt = 0; nt < 4; ++nt) {
        f32x4 a = (f32x4){0.f, 0.f, 0.f, 0.f};
#pragma unroll
        for (int ks = 0; ks < 2; ++ks) {
            const bf16x8 bs = *(const bf16x8*)&ShL[(nt * 16 + lnlo) * LDK + ks * 32 + quad * 8];
            a = __builtin_amdgcn_mfma_f32_16x16x32_bf16(aQ[ks], bs, a, 0, 0, 0);
        }
        o[nt] = a;
    }

    // ---- intra scores ----
    f32x4 acc[4];
#pragma unroll
    for (int nt = 0; nt < 4; ++nt) {
        f32x4 a = (f32x4){0.f, 0.f, 0.f, 0.f};
#pragma unroll
        for (int ks = 0; ks < 2; ++ks) {
            const bf16x8 bk = *(const bf16x8*)&Ks[(nt * 16 + lnlo) * LDK + ks * 32 + quad * 8];
            a = __builtin_amdgcn_mfma_f32_16x16x32_bf16(aQ[ks], bk, a, 0, 0, 0);
        }
        acc[nt] = a;
    }

    // scale cross by scale * lam^(i_local)
#pragma unroll
    for (int nt = 0; nt < 4; ++nt)
#pragma unroll
        for (int r = 0; r < 4; ++r) o[nt][r] *= rf[r] * scale;

    __syncthreads();   // all waves done reading ShL before it becomes Ws

    // ---- decay*scale*causal; C-layout -> A-layout via LDS ----
#pragma unroll
    for (int nt = 0; nt < 4; ++nt) {
        const int jn = nt * 16 + lnlo;
        const float cf = scale * exp2f(-(float)jn * sh);
#pragma unroll
        for (int r = 0; r < 4; ++r) {
            const int ri = wv * 16 + quad * 4 + r;
            float wgt = acc[nt][r] * rf[r] * cf;
            if (ri < jn) wgt = 0.0f;
            ShL[ri * LDK + jn] = f2bf(wgt);
        }
    }
    const bf16x8 aW0 = *(const bf16x8*)&ShL[(wv * 16 + lnlo) * LDK + quad * 8];
    const bf16x8 aW1 = *(const bf16x8*)&ShL[(wv * 16 + lnlo) * LDK + 32 + quad * 8];

    // ---- O += P V ----
#pragma unroll
    for (int nt = 0; nt < 4; ++nt) {
        const bf16x8 bv0 = *(const bf16x8*)&Vt[(nt * 16 + lnlo) * LDK + quad * 8];
        const bf16x8 bv1 = *(const bf16x8*)&Vt[(nt * 16 + lnlo) * LDK + 32 + quad * 8];
        o[nt] = __builtin_amdgcn_mfma_f32_16x16x32_bf16(aW0, bv0, o[nt], 0, 0, 0);
        o[nt] = __builtin_amdgcn_mfma_f32_16x16x32_bf16(aW1, bv1, o[nt], 0, 0, 0);
    }

    // ---- epilogue ----
#pragma unroll
    for (int nt = 0; nt < 4; ++nt)
#pragma unroll
        for (int r = 0; r < 4; ++r)
            op[(size_t)(wv * 16 + quad * 4 + r) * DHEAD + nt * 16 + lnlo] = o[nt][r];
}

extern "C" void kernel_launch(void* const* d_in, const int* in_sizes, int n_in,
                              void* d_out, int out_size, void* d_ws, size_t ws_size,
                              hipStream_t stream) {
    (void)in_sizes; (void)n_in; (void)out_size; (void)ws_size;
    const float* q = (const float*)d_in[0];
    const float* k = (const float*)d_in[1];
    const float* v = (const float*)d_in[2];
    float* o  = (float*)d_out;
    unsigned short* Ug = (unsigned short*)d_ws;                                  // 8 MB bf16
    unsigned short* Sg = (unsigned short*)((char*)d_ws + (size_t)BH * NC * 4096 * 2);  // 8 MB bf16

    dim3 blk(256, 1, 1);
    ret_p1<<<dim3(NC - 1, BH, 1), blk, 0, stream>>>(k, v, Ug);   // U_31 never consumed
    ret_p2<<<dim3(16, BH, 1), blk, 0, stream>>>(Ug, Sg);
    ret_p3<<<dim3(NC, BH, 1), blk, 0, stream>>>(q, k, v, Sg, o);
}